// Round 12
// baseline (5958.044 us; speedup 1.0000x reference)
//
#include <hip/hip_runtime.h>
#include <hip/hip_bf16.h>
#include <math.h>

#define MINN 1e-7f

// Problem dims (fixed by setup_inputs)
#define BB 64
#define SS 128
#define NCOL 3840            // 768 (W_d) + 4*768 (gates)
#define NWG_STEP 120         // 60 col-groups x 2 k-halves

typedef float f4 __attribute__((ext_vector_type(4)));
typedef short bf16x8 __attribute__((ext_vector_type(8)));
typedef float f32x4 __attribute__((ext_vector_type(4)));

__device__ __forceinline__ float artanh_c(float x) {
  x = fminf(fmaxf(x, -1.0f + 1e-6f), 1.0f - 1e-6f);
  return atanhf(x);
}
__device__ __forceinline__ float tan_k_(float x, float sq) { return tanhf(sq * x) / sq; }
__device__ __forceinline__ float artan_k_(float x, float sq) { return artanh_c(sq * x) / sq; }

// Block reduction over 256 threads (4 waves).
template <int N>
__device__ __forceinline__ void block_reduce_sum(float* v, float* red) {
#pragma unroll
  for (int m = 1; m < 64; m <<= 1) {
#pragma unroll
    for (int i = 0; i < N; ++i) v[i] += __shfl_xor(v[i], m, 64);
  }
  int wid = threadIdx.x >> 6;
  int lane = threadIdx.x & 63;
  if (lane == 0) {
#pragma unroll
    for (int i = 0; i < N; ++i) red[wid * N + i] = v[i];
  }
  __syncthreads();
#pragma unroll
  for (int i = 0; i < N; ++i) v[i] = red[i] + red[N + i] + red[2 * N + i] + red[3 * N + i];
  __syncthreads();
}

// Build combined weight matrix as bf16 hi/lo, [col][k] (k-contiguous = B-fragment ready).
__global__ __launch_bounds__(256) void k_build_cw(const float* __restrict__ W_all,
                                                  const float* __restrict__ W_d,
                                                  __hip_bfloat16* __restrict__ CWh,
                                                  __hip_bfloat16* __restrict__ CWl) {
  int col = blockIdx.x;  // 0..3839
#pragma unroll
  for (int p = 0; p < 3; ++p) {
    int k = threadIdx.x + 256 * p;
    float v;
    if (col < 768) {
      v = W_d[col * 768 + k];
    } else {
      int jm = col - 768;
      int g = jm / 768;
      int j2 = jm - g * 768;
      v = W_all[j2 * 3072 + g * 768 + k];
    }
    __hip_bfloat16 h = __float2bfloat16(v);
    CWh[(size_t)col * 768 + k] = h;
    CWl[(size_t)col * 768 + k] = __float2bfloat16(v - __bfloat162float(h));
  }
}

// Init: fp32 row-major state + bf16 hi/lo row-major copies (A-fragment ready).
__global__ __launch_bounds__(256) void k_init_state(
    const float* __restrict__ h0, const float* __restrict__ c0,
    float* __restrict__ ccR, float* __restrict__ hR,
    __hip_bfloat16* __restrict__ CH, __hip_bfloat16* __restrict__ CL,
    __hip_bfloat16* __restrict__ HH, __hip_bfloat16* __restrict__ HL) {
  int r = blockIdx.x;
#pragma unroll
  for (int p = 0; p < 3; ++p) {
    int j = threadIdx.x + 256 * p;
    float cv = c0[r * 768 + j];
    float hv = h0[r * 768 + j];
    ccR[r * 768 + j] = cv;
    hR[r * 768 + j] = hv;
    __hip_bfloat16 ch = __float2bfloat16(cv);
    CH[r * 768 + j] = ch;
    CL[r * 768 + j] = __float2bfloat16(cv - __bfloat162float(ch));
    __hip_bfloat16 hh = __float2bfloat16(hv);
    HH[r * 768 + j] = hh;
    HL[r * 768 + j] = __float2bfloat16(hv - __bfloat162float(hh));
  }
}

__global__ __launch_bounds__(256) void k_xnorm(const float* __restrict__ X,
                                               float* __restrict__ XN) {
  __shared__ float red[4];
  int r = blockIdx.x;
  float s = 0.f;
#pragma unroll
  for (int p = 0; p < 3; ++p) {
    float v = X[(size_t)r * 768 + threadIdx.x + 256 * p];
    s += v * v;
  }
#pragma unroll
  for (int m = 1; m < 64; m <<= 1) s += __shfl_xor(s, m, 64);
  if ((threadIdx.x & 63) == 0) red[threadIdx.x >> 6] = s;
  __syncthreads();
  if (threadIdx.x == 0) XN[r] = fmaxf(sqrtf(red[0] + red[1] + red[2] + red[3]), MINN);
}

// Split fp32 -> bf16 hi + bf16 lo (residual). Processes 4 elems/thread.
__global__ __launch_bounds__(256) void k_split(const float* __restrict__ src,
                                               __hip_bfloat16* __restrict__ hi,
                                               __hip_bfloat16* __restrict__ lo, int n4) {
  int i = blockIdx.x * 256 + threadIdx.x;
  if (i >= n4) return;
  f4 v = *(const f4*)(src + (size_t)i * 4);
#pragma unroll
  for (int j = 0; j < 4; ++j) {
    float x = (j == 0) ? v.x : (j == 1) ? v.y : (j == 2) ? v.z : v.w;
    __hip_bfloat16 h = __float2bfloat16(x);
    float r = x - __bfloat162float(h);
    hi[(size_t)i * 4 + j] = h;
    lo[(size_t)i * 4 + j] = __float2bfloat16(r);
  }
}

// MFMA U-path GEMM, 2-pass (xh*uh + xl*uh): OUT[i][m] = sum_k X[i][k]*U[m][k].
__global__ __launch_bounds__(256) void k_gemm_xu_mfma(
    const __hip_bfloat16* __restrict__ Xh, const __hip_bfloat16* __restrict__ Xl,
    const __hip_bfloat16* __restrict__ Uh, __hip_bfloat16* __restrict__ OUT) {
  int tid = threadIdx.x;
  int wave = tid >> 6, lane = tid & 63;
  int r = lane & 15, kg = lane >> 4;
  int i0 = blockIdx.x * 128 + wave * 32;
  int m0 = blockIdx.y * 64;
  const __hip_bfloat16* xh0 = Xh + (size_t)(i0 + r) * 768 + kg * 8;
  const __hip_bfloat16* xh1 = Xh + (size_t)(i0 + 16 + r) * 768 + kg * 8;
  const __hip_bfloat16* xl0 = Xl + (size_t)(i0 + r) * 768 + kg * 8;
  const __hip_bfloat16* xl1 = Xl + (size_t)(i0 + 16 + r) * 768 + kg * 8;
  const __hip_bfloat16* uh = Uh + (size_t)(m0 + r) * 768 + kg * 8;
  f32x4 acc[2][4];
#pragma unroll
  for (int a = 0; a < 2; ++a)
#pragma unroll
    for (int b = 0; b < 4; ++b) acc[a][b] = {0.f, 0.f, 0.f, 0.f};
  for (int k0 = 0; k0 < 768; k0 += 32) {
    bf16x8 ah0 = *(const bf16x8*)(xh0 + k0);
    bf16x8 ah1 = *(const bf16x8*)(xh1 + k0);
    bf16x8 al0 = *(const bf16x8*)(xl0 + k0);
    bf16x8 al1 = *(const bf16x8*)(xl1 + k0);
    bf16x8 bh[4];
#pragma unroll
    for (int p = 0; p < 4; ++p) bh[p] = *(const bf16x8*)(uh + p * 12288 + k0);
#pragma unroll
    for (int p = 0; p < 4; ++p) {
      acc[0][p] = __builtin_amdgcn_mfma_f32_16x16x32_bf16(ah0, bh[p], acc[0][p], 0, 0, 0);
      acc[1][p] = __builtin_amdgcn_mfma_f32_16x16x32_bf16(ah1, bh[p], acc[1][p], 0, 0, 0);
      acc[0][p] = __builtin_amdgcn_mfma_f32_16x16x32_bf16(al0, bh[p], acc[0][p], 0, 0, 0);
      acc[1][p] = __builtin_amdgcn_mfma_f32_16x16x32_bf16(al1, bh[p], acc[1][p], 0, 0, 0);
    }
  }
#pragma unroll
  for (int a = 0; a < 2; ++a)
#pragma unroll
    for (int p = 0; p < 4; ++p)
#pragma unroll
      for (int jj = 0; jj < 4; ++jj)
        OUT[(size_t)(i0 + a * 16 + kg * 4 + jj) * 3072 + m0 + p * 16 + r] =
            __float2bfloat16(acc[a][p][jj]);
}

// Fused per-step kernel: 120 WGs. All WGs: MFMA GEMM tile (cg = wg%60, kh = wg/60);
// GOUT via volatile write-through. Arrive: per-WG flag store (NO RMW chain — r10's
// regression was the 240-serialized atomicAdd). WGs 0..63 then wait on all 120 flags
// and run pw for row wg. State/weights/UG stay on cached paths (cross-launch coherent).
__global__ __launch_bounds__(256) void k_step(
    const __hip_bfloat16* __restrict__ CWh, const __hip_bfloat16* __restrict__ CWl,
    const __hip_bfloat16* __restrict__ CH, const __hip_bfloat16* __restrict__ CL,
    const __hip_bfloat16* __restrict__ HH, const __hip_bfloat16* __restrict__ HL,
    float* __restrict__ GOUT2, unsigned int* __restrict__ flags,
    const __hip_bfloat16* __restrict__ UG, const float* __restrict__ XN,
    const float* __restrict__ TS, const float* __restrict__ kptr,
    float* __restrict__ ccR, float* __restrict__ hR,
    __hip_bfloat16* __restrict__ CHo, __hip_bfloat16* __restrict__ CLo,
    __hip_bfloat16* __restrict__ HHo, __hip_bfloat16* __restrict__ HLo,
    float* __restrict__ out, int t) {
  __shared__ float red[64];
  int wg = blockIdx.x;  // 0..119
  int tid = threadIdx.x;
  unsigned int gen = (unsigned int)(t + 1);

  // ---------------- Phase G: MFMA GEMM (all 120 WGs) ----------------
  {
    int cg = wg % 60;  // col-group (64 cols); cg<12 -> c-state
    int kh = wg / 60;  // k-half
    int wave = tid >> 6, lane = tid & 63;
    int r = lane & 15, kg = lane >> 4;
    int i0 = wave * 16;
    int m0 = cg * 64;
    int kb = kh * 384;
    const __hip_bfloat16* sh = (cg < 12 ? CH : HH) + (size_t)(i0 + r) * 768 + kb + kg * 8;
    const __hip_bfloat16* sl = (cg < 12 ? CL : HL) + (size_t)(i0 + r) * 768 + kb + kg * 8;
    const __hip_bfloat16* wh = CWh + (size_t)(m0 + r) * 768 + kb + kg * 8;
    const __hip_bfloat16* wl = CWl + (size_t)(m0 + r) * 768 + kb + kg * 8;
    f32x4 acc[4];
#pragma unroll
    for (int p = 0; p < 4; ++p) acc[p] = {0.f, 0.f, 0.f, 0.f};
#pragma unroll 4
    for (int k0 = 0; k0 < 384; k0 += 32) {
      bf16x8 ah = *(const bf16x8*)(sh + k0);
      bf16x8 al = *(const bf16x8*)(sl + k0);
#pragma unroll
      for (int p = 0; p < 4; ++p) {
        bf16x8 bh = *(const bf16x8*)(wh + p * 12288 + k0);
        bf16x8 bl = *(const bf16x8*)(wl + p * 12288 + k0);
        acc[p] = __builtin_amdgcn_mfma_f32_16x16x32_bf16(ah, bh, acc[p], 0, 0, 0);
        acc[p] = __builtin_amdgcn_mfma_f32_16x16x32_bf16(al, bh, acc[p], 0, 0, 0);
        acc[p] = __builtin_amdgcn_mfma_f32_16x16x32_bf16(ah, bl, acc[p], 0, 0, 0);
      }
    }
    float* gout = GOUT2 + (size_t)kh * (BB * NCOL);
#pragma unroll
    for (int p = 0; p < 4; ++p)
#pragma unroll
      for (int jj = 0; jj < 4; ++jj)
        *(volatile float*)&gout[(size_t)(i0 + kg * 4 + jj) * NCOL + m0 + p * 16 + r] =
            acc[p][jj];
  }
  __syncthreads();  // vmcnt(0): all this WG's volatile GOUT stores at coherence point
  if (tid == 0)
    __hip_atomic_store(&flags[wg], gen, __ATOMIC_RELAXED, __HIP_MEMORY_SCOPE_AGENT);
  if (wg >= BB) return;

  // ---------------- Handoff: wait for all 120 producers (no RMW) ----------
  if (tid < NWG_STEP) {
    while (__hip_atomic_load(&flags[tid], __ATOMIC_RELAXED, __HIP_MEMORY_SCOPE_AGENT) <
           gen) {
      __builtin_amdgcn_s_sleep(4);
    }
  }
  __syncthreads();

  // ---------------- Phase P: pointwise hyperbolic update (WGs 0..63) ------
  int r = wg;
  float kk = kptr[0];
  float sq = sqrtf(-kk);
  const float* grow0 = GOUT2 + (size_t)r * NCOL;
  const float* grow1 = GOUT2 + (size_t)BB * NCOL + (size_t)r * NCOL;
  int i = r * SS + t;
  const __hip_bfloat16* urow = UG + (size_t)i * 3072;

  float cc[3], h[3], mv[3], gh[4][3], mx[4][3];
#pragma unroll
  for (int p = 0; p < 3; ++p) {
    int j = tid + 256 * p;
    cc[p] = ccR[r * 768 + j];
    h[p] = hR[r * 768 + j];
    mv[p] = *(volatile const float*)&grow0[j] + *(volatile const float*)&grow1[j];
#pragma unroll
    for (int g = 0; g < 4; ++g) {
      gh[g][p] = *(volatile const float*)&grow0[768 + g * 768 + j] +
                 *(volatile const float*)&grow1[768 + g * 768 + j];
      mx[g][p] = __bfloat162float(urow[g * 768 + j]);
    }
  }

  float sv[15];
#pragma unroll
  for (int q = 0; q < 15; ++q) sv[q] = 0.f;
#pragma unroll
  for (int p = 0; p < 3; ++p) {
    sv[0] += cc[p] * cc[p];
    sv[1] += h[p] * h[p];
    sv[2] += mv[p] * mv[p];
#pragma unroll
    for (int g = 0; g < 4; ++g) {
      sv[3 + g] += gh[g][p] * gh[g][p];
      sv[7 + g] += gh[g][p] * mx[g][p];
      sv[11 + g] += mx[g][p] * mx[g][p];
    }
  }
  block_reduce_sum<15>(sv, red);
  float c2 = sv[0], h2 = sv[1], mvn2 = sv[2];
  float xn_c = fmaxf(sqrtf(c2), MINN);
  float xn_h = fmaxf(sqrtf(h2), MINN);
  float mxn_d = fmaxf(sqrtf(mvn2), MINN);

  float r_d = (mxn_d / xn_c) * artan_k_(xn_c, sq);
  float twd = tan_k_(r_d, sq);
  float wdsc = twd / mxn_d;
  float yn_d = fmaxf(fabsf(twd), MINN);
  float lsc = (artan_k_(yn_d, sq) / yn_d) * wdsc;
  float th[3];
#pragma unroll
  for (int p = 0; p < 3; ++p) th[p] = tanhf(lsc * mv[p]);

  float uxn = XN[i];
  float ak_h = artan_k_(xn_h, sq);
  float ak_u = artan_k_(uxn, sq);
  float cAg[4], cBg[4], pscg[4];
#pragma unroll
  for (int g = 0; g < 4; ++g) {
    float ghn = fmaxf(sqrtf(sv[3 + g]), MINN);
    float tg = tan_k_((ghn / xn_h) * ak_h, sq);
    float wsc = tg / ghn;
    float w2 = tg * tg;
    float umxn = fmaxf(sqrtf(sv[11 + g]), MINN);
    float us = tan_k_((umxn / uxn) * ak_u, sq) / umxn;
    float u2 = us * us * sv[11 + g];
    float xy = wsc * us * sv[7 + g];
    float den = fmaxf(1.f - 2.f * kk * xy + kk * kk * w2 * u2, MINN);
    float a = (1.f - 2.f * kk * xy - kk * u2) / den;
    float b = (1.f + kk * w2) / den;
    float y2s = fmaxf(a * a * w2 + 2.f * a * b * xy + b * b * u2, 0.f);
    float yn = fmaxf(sqrtf(y2s), MINN);
    pscg[g] = artan_k_(yn, sq) / yn;
    cAg[g] = a * wsc;
    cBg[g] = b * us;
  }
  float gate[4][3];
#pragma unroll
  for (int g = 0; g < 4; ++g)
#pragma unroll
    for (int p = 0; p < 3; ++p)
      gate[g][p] = 1.f / (1.f + expf(-pscg[g] * (cAg[g] * gh[g][p] + cBg[g] * mx[g][p])));

  float s2v[2] = {0.f, 0.f};
#pragma unroll
  for (int p = 0; p < 3; ++p) {
    s2v[0] += th[p] * th[p];
    s2v[1] += th[p] * cc[p];
  }
  block_reduce_sum<2>(s2v, red);
  float un = fmaxf(sqrtf(s2v[0]), MINN);
  float esc = tan_k_(un, sq) / un;
  float cs1[3];
#pragma unroll
  for (int p = 0; p < 3; ++p) cs1[p] = esc * th[p];
  float d1 = esc * s2v[1];
  float s1sq = esc * esc * s2v[0];

  float tv = TS[r * SS + t];
  float xnt = fmaxf(sqrtf(768.f * tv * tv), MINN);
  float wxn_t = fmaxf(fabsf(tv) * sqrtf(s1sq), MINN);
  float s2s = tan_k_((wxn_t / xnt) * artan_k_(xnt, sq), sq) / wxn_t * tv;
  float s2sq = s2s * s2s * s1sq;

  float den_l = fmaxf(1.f + 2.f * kk * d1 + kk * kk * s1sq * c2, MINN);
  float al = (1.f + 2.f * kk * d1 - kk * c2) / den_l;
  float bl = (1.f + kk * s1sq) / den_l;
  float pcl = -al, qcl = bl;

  float xy2 = s2s * (pcl * s1sq + qcl * d1);
  float x2b = fmaxf(pcl * pcl * s1sq + 2.f * pcl * qcl * d1 + qcl * qcl * c2, 0.f);
  float y2b = s2sq;
  float den2 = fmaxf(1.f - 2.f * kk * xy2 + kk * kk * x2b * y2b, MINN);
  float a2 = (1.f - 2.f * kk * xy2 - kk * y2b) / den2;
  float b2 = (1.f + kk * x2b) / den2;
  float g1c = a2 * pcl + b2 * s2s;
  float g2c = a2 * qcl;
  float cadj[3];
#pragma unroll
  for (int p = 0; p < 3; ++p) cadj[p] = g1c * cs1[p] + g2c * cc[p];
  float adjsq = fmaxf(g1c * g1c * s1sq + 2.f * g1c * g2c * d1 + g2c * g2c * c2, 0.f);

  float wxi[3], wxf[3];
#pragma unroll
  for (int p = 0; p < 3; ++p) {
    wxi[p] = gate[1][p] * gate[3][p];
    wxf[p] = gate[0][p] * cadj[p];
  }
  float s3v[4] = {0.f, 0.f, 0.f, 0.f};
#pragma unroll
  for (int p = 0; p < 3; ++p) {
    s3v[0] += gate[3][p] * gate[3][p];
    s3v[1] += wxi[p] * wxi[p];
    s3v[2] += wxf[p] * wxf[p];
    s3v[3] += wxi[p] * wxf[p];
  }
  block_reduce_sum<4>(s3v, red);
  float xnct = fmaxf(sqrtf(s3v[0]), MINN);
  float wxni = fmaxf(sqrtf(s3v[1]), MINN);
  float psi = tan_k_((wxni / xnct) * artan_k_(xnct, sq), sq) / wxni;
  float pi2 = psi * psi * s3v[1];
  float xnadj = fmaxf(sqrtf(adjsq), MINN);
  float wxnf = fmaxf(sqrtf(s3v[2]), MINN);
  float psf = tan_k_((wxnf / xnadj) * artan_k_(xnadj, sq), sq) / wxnf;
  float pf2 = psf * psf * s3v[2];
  float xyp = psi * psf * s3v[3];
  float den3 = fmaxf(1.f - 2.f * kk * xyp + kk * kk * pi2 * pf2, MINN);
  float a3 = (1.f - 2.f * kk * xyp - kk * pf2) / den3;
  float b3 = (1.f + kk * pi2) / den3;
  float nc[3], tc[3];
#pragma unroll
  for (int p = 0; p < 3; ++p) {
    nc[p] = a3 * psi * wxi[p] + b3 * psf * wxf[p];
    tc[p] = tanhf(nc[p]);
  }
  float s4v[2] = {0.f, 0.f};
#pragma unroll
  for (int p = 0; p < 3; ++p) {
    s4v[0] += tc[p] * tc[p];
    float gt = gate[2][p] * tc[p];
    s4v[1] += gt * gt;
  }
  block_reduce_sum<2>(s4v, red);
  float unh = fmaxf(sqrtf(s4v[0]), MINN);
  float ehs = tan_k_(unh, sq) / unh;
  float Esq = ehs * ehs * s4v[0];
  float En = fmaxf(sqrtf(Esq), MINN);
  float wxno = fmaxf(ehs * sqrtf(s4v[1]), MINN);
  float pso = tan_k_((wxno / En) * artan_k_(En, sq), sq) / wxno;

  size_t BSHc = (size_t)BB * SS * 768;
#pragma unroll
  for (int p = 0; p < 3; ++p) {
    int j = tid + 256 * p;
    out[((size_t)r * SS + t) * 768 + j] = gate[2][p];  // output = o gate
    float ncv = nc[p];
    float nhv = pso * (gate[2][p] * (ehs * tc[p]));
    ccR[r * 768 + j] = ncv;
    hR[r * 768 + j] = nhv;
    __hip_bfloat16 chh = __float2bfloat16(ncv);
    CHo[r * 768 + j] = chh;
    CLo[r * 768 + j] = __float2bfloat16(ncv - __bfloat162float(chh));
    __hip_bfloat16 hhh = __float2bfloat16(nhv);
    HHo[r * 768 + j] = hhh;
    HLo[r * 768 + j] = __float2bfloat16(nhv - __bfloat162float(hhh));
    if (t == SS - 1) {
      out[BSHc + (size_t)r * 768 + j] = nhv;                    // h_last
      out[BSHc + (size_t)BB * 768 + (size_t)r * 768 + j] = ncv; // c_last
    }
  }
}

extern "C" void kernel_launch(void* const* d_in, const int* in_sizes, int n_in,
                              void* d_out, int out_size, void* d_ws, size_t ws_size,
                              hipStream_t stream) {
  const float* inputs = (const float*)d_in[0];
  const float* ts = (const float*)d_in[1];
  const float* h0 = (const float*)d_in[2];
  const float* c0 = (const float*)d_in[3];
  const float* W_all = (const float*)d_in[4];
  const float* U_all = (const float*)d_in[5];
  const float* W_d = (const float*)d_in[6];
  const float* kptr = (const float*)d_in[7];
  float* ws = (float*)d_ws;
  float* out = (float*)d_out;

  // all offsets in float units
  size_t oFLG = 0;                     // 128 uints
  size_t oCWH = 128;                   // 3840*768 bf16 = 1,474,560 fl
  size_t oCWL = oCWH + 1474560;
  size_t oCCR = oCWL + 1474560;        // fp32 state 49,152 fl each
  size_t oHR = oCCR + 49152;
  size_t oCH = oHR + 49152;            // bf16 state 24,576 fl each
  size_t oCL = oCH + 24576;
  size_t oHH = oCL + 24576;
  size_t oHL = oHH + 24576;
  size_t oGOUT = oHL + 24576;          // 2 x 245,760 fl (k-partials)
  size_t oXN = oGOUT + 2 * (size_t)BB * NCOL;
  size_t oUG = oXN + 8192;             // 12,582,912 fl
  size_t oXH = oUG + 12582912;         // 3,145,728 fl
  size_t oXL = oXH + 3145728;
  size_t oUH = oXL + 3145728;          // 1,179,648 fl
  size_t oUL = oUH + 1179648;

  unsigned int* flags = (unsigned int*)(ws + oFLG);
  __hip_bfloat16* cwh = (__hip_bfloat16*)(ws + oCWH);
  __hip_bfloat16* cwl = (__hip_bfloat16*)(ws + oCWL);
  float* ccr = ws + oCCR;
  float* hr = ws + oHR;
  __hip_bfloat16* ch = (__hip_bfloat16*)(ws + oCH);
  __hip_bfloat16* cl = (__hip_bfloat16*)(ws + oCL);
  __hip_bfloat16* hh = (__hip_bfloat16*)(ws + oHH);
  __hip_bfloat16* hl = (__hip_bfloat16*)(ws + oHL);
  float* gout = ws + oGOUT;
  float* xn = ws + oXN;
  __hip_bfloat16* ug = (__hip_bfloat16*)(ws + oUG);
  __hip_bfloat16* xhh = (__hip_bfloat16*)(ws + oXH);
  __hip_bfloat16* xll = (__hip_bfloat16*)(ws + oXL);
  __hip_bfloat16* uhh = (__hip_bfloat16*)(ws + oUH);
  __hip_bfloat16* ull = (__hip_bfloat16*)(ws + oUL);

  hipMemsetAsync(flags, 0, 512, stream);  // graph node: resets every replay
  k_build_cw<<<NCOL, 256, 0, stream>>>(W_all, W_d, cwh, cwl);
  k_init_state<<<BB, 256, 0, stream>>>(h0, c0, ccr, hr, ch, cl, hh, hl);
  k_split<<<(6291456 / 4 + 255) / 256, 256, 0, stream>>>(inputs, xhh, xll, 6291456 / 4);
  k_split<<<(2359296 / 4 + 255) / 256, 256, 0, stream>>>(U_all, uhh, ull, 2359296 / 4);
  k_gemm_xu_mfma<<<dim3(64, 48), 256, 0, stream>>>(xhh, xll, uhh, ug);
  k_xnorm<<<BB * SS, 256, 0, stream>>>(inputs, xn);

  for (int t = 0; t < SS; ++t) {
    k_step<<<NWG_STEP, 256, 0, stream>>>(cwh, cwl, ch, cl, hh, hl, gout, flags, ug, xn,
                                         ts, kptr, ccr, hr, ch, cl, hh, hl, out, t);
  }
}